// Round 13
// baseline (92.924 us; speedup 1.0000x reference)
//
#include <hip/hip_runtime.h>

typedef unsigned long long u64;
typedef unsigned int u32;
typedef _Float16 f16;

#define NN 50000
#define NE 600000
#define D  128
#define NWAVE 3125        // 50000 / 16 rows per GEMM wave-iteration
#define GB 196            // persistent GEMM blocks (4 waves x 4 iters each)
#define GSTRIDE 784       // GB * 4 waves: row-group stride between iters
#define EPB 2048          // edges per scatter block (8 per thread)
#define NB_P 293          // ceil(600000 / 2048)
#define NP 196            // partitions: col >> 8 (256 nodes each)
#define MAXCAP 3584       // slab capacity/partition (mean 3061, sigma 55: 9.5σ)
#define NSTRIP 2          // hop strips: 64 fp16 cols = 128B = one full line
#define GS 1563           // hop blocks per strip: ceil(50000/32)

typedef __attribute__((ext_vector_type(8))) __bf16 bf16x8;
typedef __attribute__((ext_vector_type(8))) unsigned short us8;
typedef __attribute__((ext_vector_type(8))) f16 f16x8;
typedef __attribute__((ext_vector_type(4))) float f32x4;

__device__ __forceinline__ unsigned short f2bf(float f) {
    u32 u = __float_as_uint(f);
    return (unsigned short)((u + 0x7FFFu + ((u >> 16) & 1u)) >> 16);  // RNE
}
__device__ __forceinline__ float bf2f(unsigned short h) {
    return __uint_as_float((u32)h << 16);
}

// ---------------------------------------------------------------------------
// Fused kernel. Blocks [0, NB_P): SCATTER — LDS-count the block's 2048 edges
//   by partition, reserve slab space with ONE device atomicAdd per touched
//   partition (57k total), write packed edges (w|row|colloc u64) into slabs.
//   pcur holds PARTITION-LOCAL offsets (memset-0 init — wprep launch gone);
//   slab slot = p*MAXCAP + off + lr.
// Blocks [NB_P, NB_P+GB): PERSISTENT GEMM h16 = fp16(x @ W^T), split-bf16
//   MFMA. W converted in-block to frag-order hi/lo LDS tables (196 blocks;
//   r9 A/B showed conversion is off the critical path — it overlaps the
//   cold x-loads). Each wave loops 4 row-groups with next-iter x-loads
//   prefetched. Output fp16 strip-major [2][NN][64].
// ---------------------------------------------------------------------------
__global__ __launch_bounds__(256) void gemm_scatter(
    const float* __restrict__ x, const float* __restrict__ W,
    f16* __restrict__ h16, const int* __restrict__ row,
    const int* __restrict__ col, const float* __restrict__ w,
    int* __restrict__ pcur, u64* __restrict__ part) {
    const int t = threadIdx.x;
    __shared__ us8 WH[2048];  // 32 KB hi; reused as bins/off0/cur (scatter)
    __shared__ us8 WL[2048];  // 32 KB lo

    if (blockIdx.x < NB_P) {
        // ---- scatter role ----
        int* bins = (int*)WH;        // [256] (NP used)
        int* off0 = bins + 256;      // [256] partition-local slab base
        int* cur  = off0 + 256;      // [256]
        for (int i = t; i < NP; i += 256) { bins[i] = 0; cur[i] = 0; }
        __syncthreads();
        const int e0 = blockIdx.x * EPB + t;
        int cc[8];
#pragma unroll
        for (int s = 0; s < 8; ++s) {
            const int e = e0 + s * 256;
            cc[s] = (e < NE) ? col[e] : -1;
            if (cc[s] >= 0) atomicAdd(&bins[cc[s] >> 8], 1);
        }
        __syncthreads();
        for (int i = t; i < NP; i += 256)
            off0[i] = bins[i] ? atomicAdd(&pcur[i], bins[i]) : 0;
        __syncthreads();
#pragma unroll
        for (int s = 0; s < 8; ++s) {
            const int e = e0 + s * 256;
            if (e < NE) {
                const int c = cc[s];
                const int p = c >> 8;
                const int lr = atomicAdd(&cur[p], 1);
                part[(size_t)p * MAXCAP + off0[p] + lr] =
                    ((u64)__float_as_uint(w[e]) << 32) |
                    ((u32)row[e] << 8) | (u32)(c & 255);
            }
        }
        return;
    }

    // ---- persistent GEMM role ----
    const int wid = (blockIdx.x - NB_P) * 4 + (t >> 6);
    const int lane = t & 63;
    const int l15 = lane & 15, l4 = lane >> 4;

    // issue iter-0 x loads (128B/lane) before W conversion so they overlap it
    int g = (wid < NWAVE) ? wid : NWAVE - 1;
    const float* px = x + (size_t)(g * 16 + l15) * D + l4 * 8;
    float4 ar[8];
#pragma unroll
    for (int c = 0; c < 4; ++c) {
        ar[2 * c]     = *(const float4*)(px + c * 32);
        ar[2 * c + 1] = *(const float4*)(px + c * 32 + 4);
    }

    // convert W -> frag-order split-bf16 LDS tables (L2-resident source).
    // chunk i = kc4*512 + nt*64 + ln holds W[nt*16+(ln&15)][kc4*32+(ln>>4)*8+e]
#pragma unroll
    for (int s = 0; s < 8; ++s) {
        const int i = s * 256 + t;
        const int ln = i & 63, ntt = (i >> 6) & 7, kc4 = i >> 9;
        const float* pw =
            W + (size_t)(ntt * 16 + (ln & 15)) * D + kc4 * 32 + (ln >> 4) * 8;
        float v[8];
        *(float4*)&v[0] = *(const float4*)pw;
        *(float4*)&v[4] = *(const float4*)(pw + 4);
        us8 hi, lo;
#pragma unroll
        for (int j = 0; j < 8; ++j) {
            const unsigned short hb = f2bf(v[j]);
            hi[j] = hb;
            lo[j] = f2bf(v[j] - bf2f(hb));
        }
        WH[i] = hi;
        WL[i] = lo;
    }
    __syncthreads();

#pragma unroll
    for (int l = 0; l < 4; ++l) {
        // prefetch next iteration's x rows (independent of this iter's MFMA)
        float4 an[8];
        int gn = wid + (l + 1) * GSTRIDE;
        if (gn >= NWAVE) gn = NWAVE - 1;
        if (l < 3) {
            const float* pn = x + (size_t)(gn * 16 + l15) * D + l4 * 8;
#pragma unroll
            for (int c = 0; c < 4; ++c) {
                an[2 * c]     = *(const float4*)(pn + c * 32);
                an[2 * c + 1] = *(const float4*)(pn + c * 32 + 4);
            }
        }

        f32x4 acc[8];
#pragma unroll
        for (int nt = 0; nt < 8; ++nt) acc[nt] = (f32x4){0.f, 0.f, 0.f, 0.f};

#pragma unroll
        for (int c = 0; c < 4; ++c) {
            float v[8];
            *(float4*)&v[0] = ar[2 * c];
            *(float4*)&v[4] = ar[2 * c + 1];
            us8 hiu, lou;
#pragma unroll
            for (int j = 0; j < 8; ++j) {
                const unsigned short hb = f2bf(v[j]);
                hiu[j] = hb;
                lou[j] = f2bf(v[j] - bf2f(hb));
            }
            const bf16x8 ah = *(const bf16x8*)&hiu;
            const bf16x8 al = *(const bf16x8*)&lou;
#pragma unroll
            for (int nt = 0; nt < 8; ++nt) {
                const bf16x8 bh = *(const bf16x8*)&WH[c * 512 + nt * 64 + lane];
                const bf16x8 bl = *(const bf16x8*)&WL[c * 512 + nt * 64 + lane];
                acc[nt] = __builtin_amdgcn_mfma_f32_16x16x32_bf16(ah, bh, acc[nt], 0, 0, 0);
                acc[nt] = __builtin_amdgcn_mfma_f32_16x16x32_bf16(al, bh, acc[nt], 0, 0, 0);
                acc[nt] = __builtin_amdgcn_mfma_f32_16x16x32_bf16(ah, bl, acc[nt], 0, 0, 0);
            }
        }

        // epilogue: C/D layout col = lane&15, row = (lane>>4)*4 + r.
        // fp16 strip-major [2][NN][64]: strip = nt>>2, col = (nt&3)*16 + cl.
        const int row0 = g * 16;
#pragma unroll
        for (int nt = 0; nt < 8; ++nt) {
            f16* o = h16 + (size_t)(nt >> 2) * ((size_t)NN * 64) +
                     (nt & 3) * 16 + l15;
#pragma unroll
            for (int r = 0; r < 4; ++r)
                o[(size_t)(row0 + l4 * 4 + r) * 64] = (f16)acc[nt][r];
        }

        g = gn;
#pragma unroll
        for (int i = 0; i < 8; ++i) ar[i] = an[i];
    }
}

// ---------------------------------------------------------------------------
// per-partition CSR finish (slab coordinates). Block p owns nodes
// [p*256, p*256+256) and slab edges [p*MAXCAP, p*MAXCAP+pcur[p]).
// Slab cached in LDS (<=28KB) -> part read from global ONCE (was twice).
// LDS count + float weighted-degree -> dinv; LDS scan -> base/kcnt; pass 2
// is a pure reorder: sedge.y = RAW w (both dinv factors applied in the hop).
// Edge lists stay source-quarter-ordered (neutral-measured, kept).
__global__ __launch_bounds__(256) void csr_k(
    const u64* __restrict__ part, const int* __restrict__ pcur,
    int* __restrict__ base, int* __restrict__ kcnt,
    float* __restrict__ dinv, int2* __restrict__ sedge) {
    __shared__ u64 eL[MAXCAP];     // 28 KB slab cache
    __shared__ u32 cntQ[4][256];   // per-(quarter, node) counts
    __shared__ int curQ[4][256];   // per-(quarter, node) cursors
    __shared__ float wsL[256];     // weighted degree
    __shared__ int sw[256];
    const int p = blockIdx.x, tid = threadIdx.x;
    const int ne = pcur[p];
    const u64* ps = part + (size_t)p * MAXCAP;

    for (int j = tid; j < ne; j += 256) eL[j] = ps[j];
#pragma unroll
    for (int q = 0; q < 4; ++q) cntQ[q][tid] = 0u;
    wsL[tid] = 0.f;
    __syncthreads();
    for (int j = tid; j < ne; j += 256) {
        const u64 pk = eL[j];
        const int cl = (int)(pk & 255u);
        const int r = (int)((pk >> 8) & 0xFFFFu);
        const int q = (r >= 37500) ? 3 : (r >= 25000) ? 2 : (r >= 12500) ? 1 : 0;
        atomicAdd(&cntQ[q][cl], 1u);
        atomicAdd(&wsL[cl], __uint_as_float((u32)(pk >> 32)));
    }
    __syncthreads();

    const int node = p * 256 + tid;
    const float di = rsqrtf(1.0f + wsL[tid]);  // deg = 1 (self) + sum_in w
    const int c0 = (int)cntQ[0][tid], c1 = (int)cntQ[1][tid];
    const int c2 = (int)cntQ[2][tid], c3 = (int)cntQ[3][tid];
    const int myc = c0 + c1 + c2 + c3;
    sw[tid] = myc;
    __syncthreads();
    for (int off = 1; off < 256; off <<= 1) {
        int tv = (tid >= off) ? sw[tid - off] : 0;
        __syncthreads();
        if (tid >= off) sw[tid] += tv;
        __syncthreads();
    }
    const int excl = sw[tid] - myc;
    if (node < NN) {
        dinv[node] = di;
        base[node] = p * MAXCAP + excl;
        kcnt[node] = myc;
    }
    curQ[0][tid] = excl;
    curQ[1][tid] = excl + c0;
    curQ[2][tid] = excl + c0 + c1;
    curQ[3][tid] = excl + c0 + c1 + c2;
    __syncthreads();

    for (int j = tid; j < ne; j += 256) {
        const u64 pk = eL[j];
        const int cl = (int)(pk & 255u);
        const int r = (int)((pk >> 8) & 0xFFFFu);
        const int q = (r >= 37500) ? 3 : (r >= 25000) ? 2 : (r >= 12500) ? 1 : 0;
        const int lr = atomicAdd(&curQ[q][cl], 1);
        int2 ed;
        ed.x = r;
        ed.y = (int)(u32)(pk >> 32);  // RAW w; dinv factors applied in hop
        sedge[(size_t)p * MAXCAP + lr] = ed;
    }
}

// ---------------------------------------------------------------------------
// one hop: dst[n] = dinv[n]^2 * src[n] + dinv[n] * sum_in (w*dinv[r])*src[r]
// sedge.y = raw w; dinv[r] applied in-loop (L2-resident table), dinv[n]
// applied once in the epilogue (wave-uniform scalar).
// fp16 strip-major [2][NN][64]: each gather = exactly one 128B line.
// 8-lane groups (fp16x8); blockIdx.y = strip. unroll 4 (unroll 8 blew the
// 64-VGPR occupancy cliff in round 8, +17 µs). Slab CSR: b = base[node],
// k = kcnt[node].
// OUTF=0: write fp16 strip-major; OUTF=1: write fp32 out.
// ---------------------------------------------------------------------------
template <int OUTF>
__global__ __launch_bounds__(256) void hop_kernel(
    const f16* __restrict__ src, f16* __restrict__ dst16,
    float* __restrict__ dstf, const int2* __restrict__ sedge,
    const int* __restrict__ base, const int* __restrict__ kcnt,
    const float* __restrict__ dinv) {
    const int node = blockIdx.x * 32 + (threadIdx.x >> 3);
    if (node >= NN) return;
    const int strip = blockIdx.y;
    const int lo8 = (threadIdx.x & 7) * 8;
    const f16* hs = src + (size_t)strip * ((size_t)NN * 64) + lo8;

    const int b = base[node];
    const int k = kcnt[node];

    float acc[8] = {0.f, 0.f, 0.f, 0.f, 0.f, 0.f, 0.f, 0.f};
#pragma unroll 4
    for (int j = 0; j < k; ++j) {
        const int2 ed = sedge[b + j];
        const f16x8 hv = *(const f16x8*)(hs + (size_t)ed.x * 64);
        const float nm = __int_as_float(ed.y) * dinv[ed.x];
#pragma unroll
        for (int i = 0; i < 8; ++i) acc[i] = fmaf(nm, (float)hv[i], acc[i]);
    }
    const float di = dinv[node];
    const float d2 = di * di;
    const f16x8 sv = *(const f16x8*)(hs + (size_t)node * 64);
#pragma unroll
    for (int i = 0; i < 8; ++i) acc[i] = fmaf(d2, (float)sv[i], di * acc[i]);

    if (OUTF) {
        float* o = dstf + (size_t)node * D + strip * 64 + lo8;
        *(float4*)&o[0] = make_float4(acc[0], acc[1], acc[2], acc[3]);
        *(float4*)&o[4] = make_float4(acc[4], acc[5], acc[6], acc[7]);
    } else {
        f16x8 ov;
#pragma unroll
        for (int i = 0; i < 8; ++i) ov[i] = (f16)acc[i];
        *(f16x8*)(dst16 + (size_t)strip * ((size_t)NN * 64) + (size_t)node * 64 + lo8) = ov;
    }
}

// ---------------------------------------------------------------------------
extern "C" void kernel_launch(void* const* d_in, const int* in_sizes, int n_in,
                              void* d_out, int out_size, void* d_ws,
                              size_t ws_size, hipStream_t stream) {
    const float* x  = (const float*)d_in[0];
    const int*   ei = (const int*)d_in[1];  // [2, NE]: row then col
    const float* w  = (const float*)d_in[2];
    const float* W  = (const float*)d_in[3];
    float* out = (float*)d_out;

    const int* row = ei;
    const int* col = ei + NE;

    // workspace carve-up (~31.9 MB)
    f16* h16a = (f16*)d_ws;                          // 2*NN*64 f16 = 12.8MB
    f16* h16b = h16a + (size_t)2 * NN * 64;          // 12.8MB
    u64* part = (u64*)h16b;                          // 5.6MB alias (dead before hop1)
    int* pcur = (int*)(h16b + (size_t)2 * NN * 64);  // NP (partition-local)
    int* base = pcur + NP;                           // NN
    int* kcnt = base + NN;                           // NN
    float* dinv = (float*)(kcnt + NN);               // NN
    int2* sedge = (int2*)(dinv + NN);                // NP*MAXCAP int2 = 5.6MB

    hipMemsetAsync(pcur, 0, (size_t)NP * sizeof(int), stream);
    gemm_scatter<<<NB_P + GB, 256, 0, stream>>>(x, W, h16a, row, col, w,
                                                pcur, part);
    csr_k<<<NP, 256, 0, stream>>>(part, pcur, base, kcnt, dinv, sedge);

    hop_kernel<0><<<dim3(GS, NSTRIP), 256, 0, stream>>>(h16a, h16b, nullptr,
                                                        sedge, base, kcnt, dinv);
    hop_kernel<1><<<dim3(GS, NSTRIP), 256, 0, stream>>>(h16b, nullptr, out,
                                                        sedge, base, kcnt, dinv);
}

// Round 14
// 90.411 us; speedup vs baseline: 1.0278x; 1.0278x over previous
//
#include <hip/hip_runtime.h>

typedef unsigned long long u64;
typedef unsigned int u32;
typedef _Float16 f16;

#define NN 50000
#define NE 600000
#define D  128
#define NWAVE 3125        // 50000 / 16 rows per GEMM wave-iteration
#define GB 196            // persistent GEMM blocks (4 waves x 4 iters each)
#define GSTRIDE 784       // GB * 4 waves: row-group stride between iters
#define EPB 2048          // edges per scatter block (8 per thread)
#define NB_P 293          // ceil(600000 / 2048)
#define NP 196            // partitions: col >> 8 (256 nodes each)
#define MAXCAP 3584       // slab capacity/partition (mean 3061, sigma 55: 9.5σ)
#define NSTRIP 2          // hop strips: 64 fp16 cols = 128B = one full line
#define GS 1563           // hop blocks per strip: ceil(50000/32)

typedef __attribute__((ext_vector_type(8))) __bf16 bf16x8;
typedef __attribute__((ext_vector_type(8))) unsigned short us8;
typedef __attribute__((ext_vector_type(8))) f16 f16x8;
typedef __attribute__((ext_vector_type(4))) float f32x4;

__device__ __forceinline__ unsigned short f2bf(float f) {
    u32 u = __float_as_uint(f);
    return (unsigned short)((u + 0x7FFFu + ((u >> 16) & 1u)) >> 16);  // RNE
}
__device__ __forceinline__ float bf2f(unsigned short h) {
    return __uint_as_float((u32)h << 16);
}

// ---------------------------------------------------------------------------
// wprep: convert W ONCE into frag-order split-bf16 tables (2048 chunks) AND
// init the 196 partition slab cursors (pcur[p] = p*MAXCAP).
// ---------------------------------------------------------------------------
__global__ __launch_bounds__(256) void wprep(const float* __restrict__ W,
                                             us8* __restrict__ Whi,
                                             us8* __restrict__ Wlo,
                                             int* __restrict__ pcur) {
    const int i = blockIdx.x * 256 + threadIdx.x;
    if (i < NP) pcur[i] = i * MAXCAP;
    if (i < 2048) {
        const int ln = i & 63, nt = (i >> 6) & 7, kc4 = i >> 9;
        const float* p =
            W + (size_t)(nt * 16 + (ln & 15)) * D + kc4 * 32 + (ln >> 4) * 8;
        float v[8];
        *(float4*)&v[0] = *(const float4*)p;
        *(float4*)&v[4] = *(const float4*)(p + 4);
        us8 hi, lo;
#pragma unroll
        for (int j = 0; j < 8; ++j) {
            const unsigned short hb = f2bf(v[j]);
            hi[j] = hb;
            lo[j] = f2bf(v[j] - bf2f(hb));
        }
        Whi[i] = hi;
        Wlo[i] = lo;
    }
}

// ---------------------------------------------------------------------------
// Fused kernel. Blocks [0, NB_P): SCATTER — LDS-count the block's 2048 edges
//   by partition, reserve slab space with ONE device atomicAdd per touched
//   partition (57k total), write packed edges (w|row|colloc u64) into slabs.
// Blocks [NB_P, NB_P+GB): PERSISTENT GEMM h16 = fp16(x @ W^T), split-bf16
//   MFMA. W staged to LDS ONCE per block; each wave loops 4 row-groups with
//   next-iter x-loads prefetched. Output fp16 strip-major [2][NN][64].
// ---------------------------------------------------------------------------
__global__ __launch_bounds__(256) void gemm_scatter(
    const float* __restrict__ x, const us8* __restrict__ Whi,
    const us8* __restrict__ Wlo, f16* __restrict__ h16,
    const int* __restrict__ row, const int* __restrict__ col,
    const float* __restrict__ w, int* __restrict__ pcur,
    u64* __restrict__ part) {
    const int t = threadIdx.x;
    __shared__ us8 WH[2048];  // 32 KB hi; reused as bins/off0/cur (scatter)
    __shared__ us8 WL[2048];  // 32 KB lo

    if (blockIdx.x < NB_P) {
        // ---- scatter role ----
        int* bins = (int*)WH;        // [256] (NP used)
        int* off0 = bins + 256;      // [256]
        int* cur  = off0 + 256;      // [256]
        for (int i = t; i < NP; i += 256) { bins[i] = 0; cur[i] = 0; }
        __syncthreads();
        const int e0 = blockIdx.x * EPB + t;
        int cc[8];
#pragma unroll
        for (int s = 0; s < 8; ++s) {
            const int e = e0 + s * 256;
            cc[s] = (e < NE) ? col[e] : -1;
            if (cc[s] >= 0) atomicAdd(&bins[cc[s] >> 8], 1);
        }
        __syncthreads();
        for (int i = t; i < NP; i += 256)
            off0[i] = bins[i] ? atomicAdd(&pcur[i], bins[i]) : 0;
        __syncthreads();
#pragma unroll
        for (int s = 0; s < 8; ++s) {
            const int e = e0 + s * 256;
            if (e < NE) {
                const int c = cc[s];
                const int p = c >> 8;
                const int lr = atomicAdd(&cur[p], 1);
                part[off0[p] + lr] = ((u64)__float_as_uint(w[e]) << 32) |
                                     ((u32)row[e] << 8) | (u32)(c & 255);
            }
        }
        return;
    }

    // ---- persistent GEMM role ----
    const int wid = (blockIdx.x - NB_P) * 4 + (t >> 6);
    const int lane = t & 63;
    const int l15 = lane & 15, l4 = lane >> 4;

    // issue iter-0 x loads (128B/lane) before staging so they overlap it
    int g = (wid < NWAVE) ? wid : NWAVE - 1;
    const float* px = x + (size_t)(g * 16 + l15) * D + l4 * 8;
    float4 ar[8];
#pragma unroll
    for (int c = 0; c < 4; ++c) {
        ar[2 * c]     = *(const float4*)(px + c * 32);
        ar[2 * c + 1] = *(const float4*)(px + c * 32 + 4);
    }

    // stage pre-converted tables ONCE (64KB, plain b128 copies, L2-resident)
#pragma unroll
    for (int i = 0; i < 8; ++i) {
        WH[t + i * 256] = Whi[t + i * 256];
        WL[t + i * 256] = Wlo[t + i * 256];
    }
    __syncthreads();

#pragma unroll
    for (int l = 0; l < 4; ++l) {
        // prefetch next iteration's x rows (independent of this iter's MFMA)
        float4 an[8];
        int gn = wid + (l + 1) * GSTRIDE;
        if (gn >= NWAVE) gn = NWAVE - 1;
        if (l < 3) {
            const float* pn = x + (size_t)(gn * 16 + l15) * D + l4 * 8;
#pragma unroll
            for (int c = 0; c < 4; ++c) {
                an[2 * c]     = *(const float4*)(pn + c * 32);
                an[2 * c + 1] = *(const float4*)(pn + c * 32 + 4);
            }
        }

        f32x4 acc[8];
#pragma unroll
        for (int nt = 0; nt < 8; ++nt) acc[nt] = (f32x4){0.f, 0.f, 0.f, 0.f};

#pragma unroll
        for (int c = 0; c < 4; ++c) {
            float v[8];
            *(float4*)&v[0] = ar[2 * c];
            *(float4*)&v[4] = ar[2 * c + 1];
            us8 hiu, lou;
#pragma unroll
            for (int j = 0; j < 8; ++j) {
                const unsigned short hb = f2bf(v[j]);
                hiu[j] = hb;
                lou[j] = f2bf(v[j] - bf2f(hb));
            }
            const bf16x8 ah = *(const bf16x8*)&hiu;
            const bf16x8 al = *(const bf16x8*)&lou;
#pragma unroll
            for (int nt = 0; nt < 8; ++nt) {
                const bf16x8 bh = *(const bf16x8*)&WH[c * 512 + nt * 64 + lane];
                const bf16x8 bl = *(const bf16x8*)&WL[c * 512 + nt * 64 + lane];
                acc[nt] = __builtin_amdgcn_mfma_f32_16x16x32_bf16(ah, bh, acc[nt], 0, 0, 0);
                acc[nt] = __builtin_amdgcn_mfma_f32_16x16x32_bf16(al, bh, acc[nt], 0, 0, 0);
                acc[nt] = __builtin_amdgcn_mfma_f32_16x16x32_bf16(ah, bl, acc[nt], 0, 0, 0);
            }
        }

        // epilogue: C/D layout col = lane&15, row = (lane>>4)*4 + r.
        // fp16 strip-major [2][NN][64]: strip = nt>>2, col = (nt&3)*16 + cl.
        const int row0 = g * 16;
#pragma unroll
        for (int nt = 0; nt < 8; ++nt) {
            f16* o = h16 + (size_t)(nt >> 2) * ((size_t)NN * 64) +
                     (nt & 3) * 16 + l15;
#pragma unroll
            for (int r = 0; r < 4; ++r)
                o[(size_t)(row0 + l4 * 4 + r) * 64] = (f16)acc[nt][r];
        }

        g = gn;
#pragma unroll
        for (int i = 0; i < 8; ++i) ar[i] = an[i];
    }
}

// ---------------------------------------------------------------------------
// per-partition CSR finish (slab coordinates). Block p owns nodes
// [p*256, p*256+256) and slab edges [p*MAXCAP, pcur[p]). LDS count + float
// weighted-degree -> dinv; LDS scan -> base[node] + kcnt[node]; scatter
// sedge with PARTIAL norm w*dinv[col]. Edge lists ordered by SOURCE-QUARTER
// (measured-neutral, kept: no cost, occasionally helps locality).
__global__ __launch_bounds__(256) void csr_k(
    const u64* __restrict__ part, const int* __restrict__ pcur,
    int* __restrict__ base, int* __restrict__ kcnt,
    float* __restrict__ dinv, int2* __restrict__ sedge) {
    __shared__ u32 cntQ[4][256];   // per-(quarter, node) counts
    __shared__ int curQ[4][256];   // per-(quarter, node) cursors
    __shared__ float wsL[256];     // weighted degree, then reused as dinv
    __shared__ int sw[256];
    const int p = blockIdx.x, tid = threadIdx.x;
    const int eb = p * MAXCAP, ee = pcur[p];

#pragma unroll
    for (int q = 0; q < 4; ++q) cntQ[q][tid] = 0u;
    wsL[tid] = 0.f;
    __syncthreads();
    for (int e = eb + tid; e < ee; e += 256) {
        const u64 pk = part[e];
        const int cl = (int)(pk & 255u);
        const int r = (int)((pk >> 8) & 0xFFFFu);
        const int q = (r >= 37500) ? 3 : (r >= 25000) ? 2 : (r >= 12500) ? 1 : 0;
        atomicAdd(&cntQ[q][cl], 1u);
        atomicAdd(&wsL[cl], __uint_as_float((u32)(pk >> 32)));
    }
    __syncthreads();

    const int node = p * 256 + tid;
    const float di = rsqrtf(1.0f + wsL[tid]);  // deg = 1 (self) + sum_in w
    const int c0 = (int)cntQ[0][tid], c1 = (int)cntQ[1][tid];
    const int c2 = (int)cntQ[2][tid], c3 = (int)cntQ[3][tid];
    const int myc = c0 + c1 + c2 + c3;
    sw[tid] = myc;
    __syncthreads();
    for (int off = 1; off < 256; off <<= 1) {
        int tv = (tid >= off) ? sw[tid - off] : 0;
        __syncthreads();
        if (tid >= off) sw[tid] += tv;
        __syncthreads();
    }
    const int excl = sw[tid] - myc;
    if (node < NN) {
        dinv[node] = di;
        base[node] = eb + excl;
        kcnt[node] = myc;
    }
    __syncthreads();
    wsL[tid] = di;
    curQ[0][tid] = excl;
    curQ[1][tid] = excl + c0;
    curQ[2][tid] = excl + c0 + c1;
    curQ[3][tid] = excl + c0 + c1 + c2;
    __syncthreads();

    for (int e = eb + tid; e < ee; e += 256) {
        const u64 pk = part[e];
        const int cl = (int)(pk & 255u);
        const int r = (int)((pk >> 8) & 0xFFFFu);
        const int q = (r >= 37500) ? 3 : (r >= 25000) ? 2 : (r >= 12500) ? 1 : 0;
        const float wv = __uint_as_float((u32)(pk >> 32));
        const int lr = atomicAdd(&curQ[q][cl], 1);
        int2 ed;
        ed.x = r;
        ed.y = __float_as_int(wv * wsL[cl]);  // partial norm: w * dinv[col]
        sedge[eb + lr] = ed;
    }
}

// ---------------------------------------------------------------------------
// one hop: dst[n] = dinv[n]^2 * src[n] + sum_in (w*dinv[r]*dinv[n]) * src[r]
// sedge.y = w*dinv[col]; dinv[row] applied in-loop (L2-resident table).
// fp16 strip-major [2][NN][64]: each gather = exactly one 128B line.
// 8-lane groups (fp16x8); blockIdx.y = strip. unroll 4 (unroll 8 blew the
// 64-VGPR occupancy cliff in round 8, +17 µs). Slab CSR: b = base[node],
// k = kcnt[node].
// OUTF=0: write fp16 strip-major; OUTF=1: write fp32 out.
// ---------------------------------------------------------------------------
template <int OUTF>
__global__ __launch_bounds__(256) void hop_kernel(
    const f16* __restrict__ src, f16* __restrict__ dst16,
    float* __restrict__ dstf, const int2* __restrict__ sedge,
    const int* __restrict__ base, const int* __restrict__ kcnt,
    const float* __restrict__ dinv) {
    const int node = blockIdx.x * 32 + (threadIdx.x >> 3);
    if (node >= NN) return;
    const int strip = blockIdx.y;
    const int lo8 = (threadIdx.x & 7) * 8;
    const f16* hs = src + (size_t)strip * ((size_t)NN * 64) + lo8;

    const int b = base[node];
    const int k = kcnt[node];

    float acc[8] = {0.f, 0.f, 0.f, 0.f, 0.f, 0.f, 0.f, 0.f};
#pragma unroll 4
    for (int j = 0; j < k; ++j) {
        const int2 ed = sedge[b + j];
        const f16x8 hv = *(const f16x8*)(hs + (size_t)ed.x * 64);
        const float nm = __int_as_float(ed.y) * dinv[ed.x];
#pragma unroll
        for (int i = 0; i < 8; ++i) acc[i] = fmaf(nm, (float)hv[i], acc[i]);
    }
    const float di = dinv[node];
    const float d2 = di * di;
    const f16x8 sv = *(const f16x8*)(hs + (size_t)node * 64);
#pragma unroll
    for (int i = 0; i < 8; ++i) acc[i] = fmaf(d2, (float)sv[i], acc[i]);

    if (OUTF) {
        float* o = dstf + (size_t)node * D + strip * 64 + lo8;
        *(float4*)&o[0] = make_float4(acc[0], acc[1], acc[2], acc[3]);
        *(float4*)&o[4] = make_float4(acc[4], acc[5], acc[6], acc[7]);
    } else {
        f16x8 ov;
#pragma unroll
        for (int i = 0; i < 8; ++i) ov[i] = (f16)acc[i];
        *(f16x8*)(dst16 + (size_t)strip * ((size_t)NN * 64) + (size_t)node * 64 + lo8) = ov;
    }
}

// ---------------------------------------------------------------------------
extern "C" void kernel_launch(void* const* d_in, const int* in_sizes, int n_in,
                              void* d_out, int out_size, void* d_ws,
                              size_t ws_size, hipStream_t stream) {
    const float* x  = (const float*)d_in[0];
    const int*   ei = (const int*)d_in[1];  // [2, NE]: row then col
    const float* w  = (const float*)d_in[2];
    const float* W  = (const float*)d_in[3];
    float* out = (float*)d_out;

    const int* row = ei;
    const int* col = ei + NE;

    // workspace carve-up (~31.9 MB)
    f16* h16a = (f16*)d_ws;                          // 2*NN*64 f16 = 12.8MB
    f16* h16b = h16a + (size_t)2 * NN * 64;          // 12.8MB
    u64* part = (u64*)h16b;                          // 5.6MB alias (dead before hop1)
    us8* Whi = (us8*)(h16b + (size_t)2 * NN * 64);   // 32KB
    us8* Wlo = Whi + 2048;                           // 32KB
    int* pcur = (int*)(Wlo + 2048);                  // NP
    int* base = pcur + NP;                           // NN
    int* kcnt = base + NN;                           // NN
    float* dinv = (float*)(kcnt + NN);               // NN
    int2* sedge = (int2*)(dinv + NN);                // NP*MAXCAP int2 = 5.6MB

    wprep<<<8, 256, 0, stream>>>(W, Whi, Wlo, pcur);
    gemm_scatter<<<NB_P + GB, 256, 0, stream>>>(x, Whi, Wlo, h16a, row, col,
                                                w, pcur, part);
    csr_k<<<NP, 256, 0, stream>>>(part, pcur, base, kcnt, dinv, sedge);

    hop_kernel<0><<<dim3(GS, NSTRIP), 256, 0, stream>>>(h16a, h16b, nullptr,
                                                        sedge, base, kcnt, dinv);
    hop_kernel<1><<<dim3(GS, NSTRIP), 256, 0, stream>>>(h16b, nullptr, out,
                                                        sedge, base, kcnt, dinv);
}